// Round 1
// baseline (275.818 us; speedup 1.0000x reference)
//
#include <hip/hip_runtime.h>
#include <hip/hip_bf16.h>

typedef short short8 __attribute__((ext_vector_type(8)));
typedef float f4 __attribute__((ext_vector_type(4)));

__device__ __forceinline__ short f2bfs(float f) {
    __hip_bfloat16 h = __float2bfloat16(f);
    return __builtin_bit_cast(short, h);
}

__device__ __forceinline__ unsigned packbf2(float a, float b, float s) {
    unsigned lo = (unsigned short)f2bfs(s * a);
    unsigned hi = (unsigned short)f2bfs(s * b);
    return (hi << 16) | lo;
}

__device__ __forceinline__ float4 add4(float4 m, float4 t) {
    float4 o; o.x = m.x + t.x; o.y = m.y + t.y; o.z = m.z + t.z; o.w = m.w + t.w;
    return o;
}

// ---------------------------------------------------------------------------
// K1: WsT[n][d] = bf16( 3*w * (wv @ wo)[d][n] )  -- fully reduced K=2048,
// pre-scaled, TRANSPOSED so K2's B-fragments are single short8 loads.
// Blocks 0..63: 64x64 tiles, 512 threads, in-block split-K (waves 0-3 low K,
// waves 4-7 high K) + LDS reduce. Blocks 64..67: bias partials b2p[4][512]
// = per-512-chunk bv@wo (raw fp32; K2 adds bo and scales).
// ---------------------------------------------------------------------------
__global__ __launch_bounds__(512) void prepW(const float* __restrict__ wv,
                                             const float* __restrict__ wo,
                                             const float* __restrict__ bv,
                                             const float* __restrict__ w,
                                             short* __restrict__ WsT,
                                             float* __restrict__ b2p) {
    constexpr int K = 2048, N = 512, NT = 32;
    const int tid = threadIdx.x;
    const int bx  = blockIdx.x;

    if (bx >= 64) {                       // 4 bias-partial blocks
        const int jb  = bx - 64;
        const int col = tid;              // 0..511
        const float* pv = bv + jb * 512;
        const float* pw = wo + (size_t)(jb * 512) * N + col;
        float s = 0.f;
#pragma unroll 8
        for (int j = 0; j < 512; ++j) s += pv[j] * pw[(size_t)j * N];
        b2p[jb * 512 + col] = s;
        return;
    }

    __shared__ float red[64][65];

    const int col0 = (bx & 7) * 64;
    const int row0 = (bx >> 3) * 64;
    const int lane = tid & 63;
    const int wave = tid >> 6;
    const int half = wave >> 2;           // in-block split-K half
    const int wq   = wave & 3;
    const int mq = wq >> 1, nq = wq & 1;
    const int ln = lane & 15, q = lane >> 4;
    const int k0 = half * 1024;

    const int rowA0 = row0 + mq * 32 + ln;
    const int rowA1 = rowA0 + 16;
    const int colB0 = col0 + nq * 32 + ln;
    const int colB1 = colB0 + 16;

    const float* pa0 = wv + (size_t)rowA0 * K + k0 + q * 8;
    const float* pa1 = wv + (size_t)rowA1 * K + k0 + q * 8;
    const float* pb  = wo + (size_t)(k0 + q * 8) * N;

    float4 a00 = *(const float4*)pa0, a01 = *(const float4*)(pa0 + 4);
    float4 a10 = *(const float4*)pa1, a11 = *(const float4*)(pa1 + 4);
    float b0r[8], b1r[8];
#pragma unroll
    for (int j = 0; j < 8; ++j) {
        b0r[j] = pb[(size_t)j * N + colB0];
        b1r[j] = pb[(size_t)j * N + colB1];
    }

    f4 acc00 = {0,0,0,0}, acc01 = {0,0,0,0}, acc10 = {0,0,0,0}, acc11 = {0,0,0,0};

    for (int t = 0; t < NT; ++t) {
        short8 af0, af1, bf0, bf1;
        af0[0]=f2bfs(a00.x); af0[1]=f2bfs(a00.y); af0[2]=f2bfs(a00.z); af0[3]=f2bfs(a00.w);
        af0[4]=f2bfs(a01.x); af0[5]=f2bfs(a01.y); af0[6]=f2bfs(a01.z); af0[7]=f2bfs(a01.w);
        af1[0]=f2bfs(a10.x); af1[1]=f2bfs(a10.y); af1[2]=f2bfs(a10.z); af1[3]=f2bfs(a10.w);
        af1[4]=f2bfs(a11.x); af1[5]=f2bfs(a11.y); af1[6]=f2bfs(a11.z); af1[7]=f2bfs(a11.w);
#pragma unroll
        for (int j = 0; j < 8; ++j) { bf0[j] = f2bfs(b0r[j]); bf1[j] = f2bfs(b1r[j]); }

        if (t + 1 < NT) {                 // prefetch next K-tile
            pa0 += 32; pa1 += 32; pb += (size_t)32 * N;
            a00 = *(const float4*)pa0; a01 = *(const float4*)(pa0 + 4);
            a10 = *(const float4*)pa1; a11 = *(const float4*)(pa1 + 4);
#pragma unroll
            for (int j = 0; j < 8; ++j) {
                b0r[j] = pb[(size_t)j * N + colB0];
                b1r[j] = pb[(size_t)j * N + colB1];
            }
        }
        acc00 = __builtin_amdgcn_mfma_f32_16x16x32_bf16(af0, bf0, acc00, 0, 0, 0);
        acc01 = __builtin_amdgcn_mfma_f32_16x16x32_bf16(af0, bf1, acc01, 0, 0, 0);
        acc10 = __builtin_amdgcn_mfma_f32_16x16x32_bf16(af1, bf0, acc10, 0, 0, 0);
        acc11 = __builtin_amdgcn_mfma_f32_16x16x32_bf16(af1, bf1, acc11, 0, 0, 0);
    }

    const int lr0 = mq * 32 + q * 4;      // local D-layout: row = q*4+r, col = ln
    const int lc0 = nq * 32 + ln;

    if (half == 1) {
#pragma unroll
        for (int r = 0; r < 4; ++r) {
            red[lr0 + r][lc0]           = acc00[r];
            red[lr0 + r][lc0 + 16]      = acc01[r];
            red[lr0 + 16 + r][lc0]      = acc10[r];
            red[lr0 + 16 + r][lc0 + 16] = acc11[r];
        }
    }
    __syncthreads();
    if (half == 0) {
        const float wsc = 3.0f * w[0];
#pragma unroll
        for (int r = 0; r < 4; ++r) {
            acc00[r] += red[lr0 + r][lc0];
            acc01[r] += red[lr0 + r][lc0 + 16];
            acc10[r] += red[lr0 + 16 + r][lc0];
            acc11[r] += red[lr0 + 16 + r][lc0 + 16];
        }
        // transposed bf16 store: WsT[col][row], rows packed in pairs (dwords)
        short* p0 = WsT + (size_t)(col0 + lc0) * 512 + row0 + lr0;
        short* p1 = WsT + (size_t)(col0 + lc0 + 16) * 512 + row0 + lr0;
        *(unsigned*)(p0)      = packbf2(acc00[0], acc00[1], wsc);
        *(unsigned*)(p0 + 2)  = packbf2(acc00[2], acc00[3], wsc);
        *(unsigned*)(p0 + 16) = packbf2(acc10[0], acc10[1], wsc);
        *(unsigned*)(p0 + 18) = packbf2(acc10[2], acc10[3], wsc);
        *(unsigned*)(p1)      = packbf2(acc01[0], acc01[1], wsc);
        *(unsigned*)(p1 + 2)  = packbf2(acc01[2], acc01[3], wsc);
        *(unsigned*)(p1 + 16) = packbf2(acc11[0], acc11[1], wsc);
        *(unsigned*)(p1 + 18) = packbf2(acc11[2], acc11[3], wsc);
    }
}

// ---------------------------------------------------------------------------
// K2: per-block 16(b)x64(n) tile of t = hid @ WsT (+ scaled bias), staged to
// LDS, then the same block streams out[l, b-tile, n-tile] = momery + t for
// all 50 l-slots. 512 blocks x 256 thr = 8 waves/CU for the HBM stream.
// B-fragments are raw short8 loads from WsT (zero conversion VALU).
// Momery loads for the first 5 slots are issued BEFORE the GEMM.
// ---------------------------------------------------------------------------
__global__ __launch_bounds__(256) void fusedTB(const float* __restrict__ hid,
                                               const short* __restrict__ WsT,
                                               const float* __restrict__ b2p,
                                               const float* __restrict__ bo,
                                               const float* __restrict__ w,
                                               const float* __restrict__ mem,
                                               float* __restrict__ out) {
    constexpr int KD = 512, NT = 16;
    constexpr size_t LS = 1024 * 512 / 4;   // float4 stride between l-slots
    __shared__ float tT[16][64];

    const int tid  = threadIdx.x;
    const int b0   = blockIdx.x * 16;       // 64 row-blocks
    const int c0   = blockIdx.y * 64;       // 8 col-blocks
    const int lane = tid & 63;
    const int wave = tid >> 6;              // wave = 16-col quadrant
    const int ln = lane & 15, q = lane >> 4;
    const int row = b0 + ln;
    const int col = c0 + wave * 16 + ln;

    // stream mapping: thread -> one float4 of the tile
    const int sr  = tid >> 4;               // 0..15 (b row)
    const int sc4 = tid & 15;               // 0..15 (float4 col)
    const size_t sbase = (size_t)(b0 + sr) * 512 + c0 + sc4 * 4;
    const float4* mp = (const float4*)(mem + sbase);
    float4*       op = (float4*)(out + sbase);
    // prefetch momery slots 0..4 under the GEMM
    float4 m0 = mp[0], m1 = mp[LS], m2 = mp[2 * LS], m3 = mp[3 * LS], m4 = mp[4 * LS];

    const float* pa  = hid + (size_t)row * KD + q * 8;
    const short* pbw = WsT + (size_t)col * KD + q * 8;

    float4 a0 = *(const float4*)pa, a1 = *(const float4*)(pa + 4);
    short8 bf = *(const short8*)pbw;
    f4 acc = {0, 0, 0, 0};

    for (int t = 0; t < NT; ++t) {
        short8 af;
        af[0]=f2bfs(a0.x); af[1]=f2bfs(a0.y); af[2]=f2bfs(a0.z); af[3]=f2bfs(a0.w);
        af[4]=f2bfs(a1.x); af[5]=f2bfs(a1.y); af[6]=f2bfs(a1.z); af[7]=f2bfs(a1.w);
        short8 bc = bf;
        if (t + 1 < NT) {
            pa += 32; pbw += 32;
            a0 = *(const float4*)pa; a1 = *(const float4*)(pa + 4);
            bf = *(const short8*)pbw;
        }
        acc = __builtin_amdgcn_mfma_f32_16x16x32_bf16(af, bc, acc, 0, 0, 0);
    }

    const float wsc  = 3.0f * w[0];
    const float bias = wsc * (b2p[col] + b2p[512 + col] + b2p[1024 + col] +
                              b2p[1536 + col] + bo[col]);
#pragma unroll
    for (int r = 0; r < 4; ++r) tT[q * 4 + r][wave * 16 + ln] = acc[r] + bias;
    __syncthreads();

    const float4 tv = *(const float4*)&tT[sr][sc4 * 4];

    op[0]      = add4(m0, tv);
    op[LS]     = add4(m1, tv);
    op[2 * LS] = add4(m2, tv);
    op[3 * LS] = add4(m3, tv);
    op[4 * LS] = add4(m4, tv);
    mp += 5 * LS; op += 5 * LS;
    for (int c = 1; c < 10; ++c) {
        m0 = mp[0]; m1 = mp[LS]; m2 = mp[2 * LS]; m3 = mp[3 * LS]; m4 = mp[4 * LS];
        op[0]      = add4(m0, tv);
        op[LS]     = add4(m1, tv);
        op[2 * LS] = add4(m2, tv);
        op[3 * LS] = add4(m3, tv);
        op[4 * LS] = add4(m4, tv);
        mp += 5 * LS; op += 5 * LS;
    }
}

extern "C" void kernel_launch(void* const* d_in, const int* in_sizes, int n_in,
                              void* d_out, int out_size, void* d_ws, size_t ws_size,
                              hipStream_t stream) {
    const float* momery = (const float*)d_in[0];   // [50,1024,512]
    const float* hid    = (const float*)d_in[1];   // [1024,512]
    const float* w      = (const float*)d_in[4];   // scalar
    const float* wv     = (const float*)d_in[13];  // [512,2048]
    const float* bv     = (const float*)d_in[14];  // [2048]
    const float* wo     = (const float*)d_in[15];  // [2048,512]
    const float* bo     = (const float*)d_in[16];  // [512]
    float* out = (float*)d_out;

    short* WsT = (short*)d_ws;                     // 512*512 bf16 = 512 KB
    float* b2p = (float*)(WsT + 262144);           // 4*512 fp32 partials

    // K1: WsT = bf16(3w * wv@wo)^T  +  b2p = bias partials
    prepW<<<dim3(68), 512, 0, stream>>>(wv, wo, bv, w, WsT, b2p);

    // K2: t-tile GEMM + fused 50-slot broadcast stream
    fusedTB<<<dim3(64, 8), 256, 0, stream>>>(hid, WsT, b2p, bo, w, momery, out);
}

// Round 2
// 260.325 us; speedup vs baseline: 1.0595x; 1.0595x over previous
//
#include <hip/hip_runtime.h>
#include <hip/hip_bf16.h>

typedef short short8 __attribute__((ext_vector_type(8)));
typedef float f4 __attribute__((ext_vector_type(4)));

__device__ __forceinline__ short f2bfs(float f) {
    __hip_bfloat16 h = __float2bfloat16(f);
    return __builtin_bit_cast(short, h);
}

#define MFMA(a, b, c) __builtin_amdgcn_mfma_f32_16x16x32_bf16(a, b, c, 0, 0, 0)

// ---------------------------------------------------------------------------
// P0: one-time operand prep.
//   blocks   0..255 : wvT[2048][512] = bf16(wv[512][2048]^T)   (64x64 LDS tiles)
//   blocks 256..511 : woT[512][2048] = bf16(wo[2048][512]^T)
//   blocks 512..767 : hidB[1024][512] = bf16(hid)
// ---------------------------------------------------------------------------
__global__ __launch_bounds__(256) void prep(const float* __restrict__ wv,
                                            const float* __restrict__ wo,
                                            const float* __restrict__ hid,
                                            short* __restrict__ wvT,
                                            short* __restrict__ woT,
                                            short* __restrict__ hidB) {
    const int bx  = blockIdx.x;
    const int tid = threadIdx.x;

    if (bx >= 512) {                       // straight cvt of hid
        const int idx = (bx - 512) * 2048 + tid * 8;
        const float4 a = *(const float4*)(hid + idx);
        const float4 b = *(const float4*)(hid + idx + 4);
        short8 o;
        o[0]=f2bfs(a.x); o[1]=f2bfs(a.y); o[2]=f2bfs(a.z); o[3]=f2bfs(a.w);
        o[4]=f2bfs(b.x); o[5]=f2bfs(b.y); o[6]=f2bfs(b.z); o[7]=f2bfs(b.w);
        *(short8*)(hidB + idx) = o;
        return;
    }

    const float* src; short* dst; int N, M, tm, tn;
    if (bx < 256) { src = wv; dst = wvT; M = 512;  N = 2048; tm = bx & 7;         tn = bx >> 3; }
    else          { src = wo; dst = woT; M = 2048; N = 512;  tm = (bx - 256) >> 3; tn = (bx - 256) & 7; }

    __shared__ short tile[64][65];
    const int r  = tid >> 4;               // 0..15
    const int c4 = tid & 15;               // 0..15
#pragma unroll
    for (int rr = 0; rr < 64; rr += 16) {
        const float4 v = *(const float4*)(src + (size_t)(tm * 64 + r + rr) * N + tn * 64 + c4 * 4);
        tile[c4 * 4 + 0][r + rr] = f2bfs(v.x);
        tile[c4 * 4 + 1][r + rr] = f2bfs(v.y);
        tile[c4 * 4 + 2][r + rr] = f2bfs(v.z);
        tile[c4 * 4 + 3][r + rr] = f2bfs(v.w);
    }
    __syncthreads();
    const int d  = tid >> 2;               // 0..63 (dst row within tile)
    const int ch = tid & 3;                // 4 x 16-short chunks per row
    short8 o0, o1;
#pragma unroll
    for (int j = 0; j < 8; ++j) { o0[j] = tile[d][ch * 16 + j]; o1[j] = tile[d][ch * 16 + 8 + j]; }
    short* p = dst + (size_t)(tn * 64 + d) * M + tm * 64 + ch * 16;
    *(short8*)p       = o0;
    *(short8*)(p + 8) = o1;
}

// ---------------------------------------------------------------------------
// G1: U[1024][2048] = hidB @ wvT^T + bv   (fp32 out, M=1024 N=2048 K=512)
// 64x64 tiles, 512 blocks, 4 waves, no LDS; A and B frags are single short8
// loads (both operands k-contiguous bf16) -> near-zero VALU in the loop.
// ---------------------------------------------------------------------------
__global__ __launch_bounds__(256) void gemmU(const short* __restrict__ hidB,
                                             const short* __restrict__ wvT,
                                             const float* __restrict__ bv,
                                             float* __restrict__ U) {
    constexpr int K = 512, N = 2048, NT = 16;
    const int tid  = threadIdx.x;
    const int col0 = blockIdx.x * 64;      // 32 col-blocks
    const int row0 = blockIdx.y * 64;      // 16 row-blocks
    const int lane = tid & 63, wave = tid >> 6;
    const int mq = wave >> 1, nq = wave & 1;
    const int ln = lane & 15, q = lane >> 4;

    const short* pa0 = hidB + (size_t)(row0 + mq * 32 + ln) * K + q * 8;
    const short* pa1 = pa0 + 16 * K;
    const short* pb0 = wvT + (size_t)(col0 + nq * 32 + ln) * K + q * 8;
    const short* pb1 = pb0 + 16 * K;

    short8 af0 = *(const short8*)pa0, af1 = *(const short8*)pa1;
    short8 bf0 = *(const short8*)pb0, bf1 = *(const short8*)pb1;
    f4 acc00 = {0,0,0,0}, acc01 = {0,0,0,0}, acc10 = {0,0,0,0}, acc11 = {0,0,0,0};

    for (int t = 0; t < NT; ++t) {
        short8 a0 = af0, a1 = af1, b0 = bf0, b1 = bf1;
        if (t + 1 < NT) {
            pa0 += 32; pa1 += 32; pb0 += 32; pb1 += 32;
            af0 = *(const short8*)pa0; af1 = *(const short8*)pa1;
            bf0 = *(const short8*)pb0; bf1 = *(const short8*)pb1;
        }
        acc00 = MFMA(a0, b0, acc00); acc01 = MFMA(a0, b1, acc01);
        acc10 = MFMA(a1, b0, acc10); acc11 = MFMA(a1, b1, acc11);
    }

    const int r0 = row0 + mq * 32 + q * 4;
    const int c0 = col0 + nq * 32 + ln;
    const float bv0 = bv[c0], bv1 = bv[c0 + 16];
#pragma unroll
    for (int r = 0; r < 4; ++r) {
        U[(size_t)(r0 + r) * N + c0]           = acc00[r] + bv0;
        U[(size_t)(r0 + r) * N + c0 + 16]      = acc01[r] + bv1;
        U[(size_t)(r0 + 16 + r) * N + c0]      = acc10[r] + bv0;
        U[(size_t)(r0 + 16 + r) * N + c0 + 16] = acc11[r] + bv1;
    }
}

// ---------------------------------------------------------------------------
// G2: t{0,1} = U @ woT^T (+bo on z==0)   (M=1024 N=512 K=2048)
// 64x64 tiles, grid (8,16,2), 512 thr = 8 waves: waves 0-3 / 4-7 take the
// two 512-K halves of this z's 1024-K chunk, LDS reduce (total split-K=4).
// A (U) is fp32 -> in-loop cvt (keeps U unrounded); B is clean short8.
// ---------------------------------------------------------------------------
__global__ __launch_bounds__(512) void gemmT(const float* __restrict__ U,
                                             const short* __restrict__ woT,
                                             const float* __restrict__ bo,
                                             float* __restrict__ t0,
                                             float* __restrict__ t1) {
    constexpr int K = 2048, N = 512, NT = 16;
    __shared__ float red[64][65];

    const int tid  = threadIdx.x;
    const int col0 = blockIdx.x * 64;
    const int row0 = blockIdx.y * 64;
    const int z    = blockIdx.z;
    const int lane = tid & 63, wave = tid >> 6;
    const int half = wave >> 2, wq = wave & 3;
    const int mq = wq >> 1, nq = wq & 1;
    const int ln = lane & 15, q = lane >> 4;
    const int k0 = z * 1024 + half * 512;

    const float* pa0 = U + (size_t)(row0 + mq * 32 + ln) * K + k0 + q * 8;
    const float* pa1 = pa0 + (size_t)16 * K;
    const short* pb0 = woT + (size_t)(col0 + nq * 32 + ln) * K + k0 + q * 8;
    const short* pb1 = pb0 + (size_t)16 * K;

    float4 a00 = *(const float4*)pa0, a01 = *(const float4*)(pa0 + 4);
    float4 a10 = *(const float4*)pa1, a11 = *(const float4*)(pa1 + 4);
    short8 bf0 = *(const short8*)pb0, bf1 = *(const short8*)pb1;

    f4 acc00 = {0,0,0,0}, acc01 = {0,0,0,0}, acc10 = {0,0,0,0}, acc11 = {0,0,0,0};

    for (int t = 0; t < NT; ++t) {
        short8 af0, af1;
        af0[0]=f2bfs(a00.x); af0[1]=f2bfs(a00.y); af0[2]=f2bfs(a00.z); af0[3]=f2bfs(a00.w);
        af0[4]=f2bfs(a01.x); af0[5]=f2bfs(a01.y); af0[6]=f2bfs(a01.z); af0[7]=f2bfs(a01.w);
        af1[0]=f2bfs(a10.x); af1[1]=f2bfs(a10.y); af1[2]=f2bfs(a10.z); af1[3]=f2bfs(a10.w);
        af1[4]=f2bfs(a11.x); af1[5]=f2bfs(a11.y); af1[6]=f2bfs(a11.z); af1[7]=f2bfs(a11.w);
        short8 b0 = bf0, b1 = bf1;
        if (t + 1 < NT) {
            pa0 += 32; pa1 += 32; pb0 += 32; pb1 += 32;
            a00 = *(const float4*)pa0; a01 = *(const float4*)(pa0 + 4);
            a10 = *(const float4*)pa1; a11 = *(const float4*)(pa1 + 4);
            bf0 = *(const short8*)pb0; bf1 = *(const short8*)pb1;
        }
        acc00 = MFMA(af0, b0, acc00); acc01 = MFMA(af0, b1, acc01);
        acc10 = MFMA(af1, b0, acc10); acc11 = MFMA(af1, b1, acc11);
    }

    const int lr0 = mq * 32 + q * 4;
    const int lc0 = nq * 32 + ln;

    if (half == 1) {
#pragma unroll
        for (int r = 0; r < 4; ++r) {
            red[lr0 + r][lc0]           = acc00[r];
            red[lr0 + r][lc0 + 16]      = acc01[r];
            red[lr0 + 16 + r][lc0]      = acc10[r];
            red[lr0 + 16 + r][lc0 + 16] = acc11[r];
        }
    }
    __syncthreads();
    if (half == 0) {
        float bb0 = 0.f, bb1 = 0.f;
        if (z == 0) { bb0 = bo[col0 + lc0]; bb1 = bo[col0 + lc0 + 16]; }
        float* C = z ? t1 : t0;
        const int r0 = row0 + lr0;
        const int c0 = col0 + lc0;
#pragma unroll
        for (int r = 0; r < 4; ++r) {
            C[(size_t)(r0 + r) * N + c0]           = acc00[r] + red[lr0 + r][lc0] + bb0;
            C[(size_t)(r0 + r) * N + c0 + 16]      = acc01[r] + red[lr0 + r][lc0 + 16] + bb1;
            C[(size_t)(r0 + 16 + r) * N + c0]      = acc10[r] + red[lr0 + 16 + r][lc0] + bb0;
            C[(size_t)(r0 + 16 + r) * N + c0 + 16] = acc11[r] + red[lr0 + 16 + r][lc0 + 16] + bb1;
        }
    }
}

// ---------------------------------------------------------------------------
// G3: out[l,b,d] = mem[l,b,d] + 3w*(t0+t1)[b,d]
// 5120 blocks x 256 thr; each thread owns one (b,d) float4 for 5 l-slots:
// t read once per 5 slots (L2), mem/out streamed nontemporally.
// ---------------------------------------------------------------------------
__global__ __launch_bounds__(256) void bcast(const float* __restrict__ mem,
                                             const float* __restrict__ t0,
                                             const float* __restrict__ t1,
                                             const float* __restrict__ w,
                                             float* __restrict__ out) {
    constexpr int P = 131072;                       // float4s per l-slot
    const int id  = blockIdx.x * 256 + threadIdx.x; // 0..1310719
    const int bd4 = id & (P - 1);
    const int grp = id >> 17;                       // 0..9 -> slots grp*5..+4
    const float s = 3.0f * w[0];
    const f4 a = ((const f4*)t0)[bd4];
    const f4 b = ((const f4*)t1)[bd4];
    const f4 tv = s * (a + b);
    const f4* mp = (const f4*)mem + (size_t)grp * 5 * P + bd4;
    f4*       op = (f4*)out       + (size_t)grp * 5 * P + bd4;
#pragma unroll
    for (int j = 0; j < 5; ++j) {
        f4 m = __builtin_nontemporal_load(mp + (size_t)j * P);
        __builtin_nontemporal_store(m + tv, op + (size_t)j * P);
    }
}

extern "C" void kernel_launch(void* const* d_in, const int* in_sizes, int n_in,
                              void* d_out, int out_size, void* d_ws, size_t ws_size,
                              hipStream_t stream) {
    const float* momery = (const float*)d_in[0];   // [50,1024,512]
    const float* hid    = (const float*)d_in[1];   // [1024,512]
    const float* w      = (const float*)d_in[4];   // scalar
    const float* wv     = (const float*)d_in[13];  // [512,2048]
    const float* bv     = (const float*)d_in[14];  // [2048]
    const float* wo     = (const float*)d_in[15];  // [2048,512]
    const float* bo     = (const float*)d_in[16];  // [512]
    float* out = (float*)d_out;

    short* wvT  = (short*)d_ws;                    // [2048][512] bf16
    short* woT  = wvT + 2048 * 512;                // [512][2048] bf16
    short* hidB = woT + 2048 * 512;                // [1024][512] bf16
    float* U    = (float*)(hidB + 1024 * 512);     // [1024][2048] fp32
    float* t0   = U + 1024 * 2048;                 // [1024][512] fp32
    float* t1   = t0 + 1024 * 512;

    prep<<<768, 256, 0, stream>>>(wv, wo, hid, wvT, woT, hidB);
    gemmU<<<dim3(32, 16), 256, 0, stream>>>(hidB, wvT, bv, U);
    gemmT<<<dim3(8, 16, 2), 512, 0, stream>>>(U, woT, bo, t0, t1);
    bcast<<<5120, 256, 0, stream>>>(momery, t0, t1, w, out);
}